// Round 8
// baseline (209.531 us; speedup 1.0000x reference)
//
#include <hip/hip_runtime.h>
#include <stdint.h>

typedef __attribute__((ext_vector_type(4))) float f32x4;
typedef __attribute__((ext_vector_type(8))) short s16x8;
typedef __attribute__((ext_vector_type(4))) short s16x4;

// Problem constants: B=2, N=2048, DIM=1024, H=16, DH=64, DI=1024, M = B*N = 4096

__device__ __forceinline__ short f2bf(float f) {
  union { float f; unsigned u; } v; v.f = f;
  unsigned r = (v.u + 0x7fff + ((v.u >> 16) & 1)) >> 16;  // RNE
  return (short)r;
}

__device__ __forceinline__ unsigned cvtpk(float lo, float hi) {
  unsigned r;
  asm("v_cvt_pk_bf16_f32 %0, %1, %2" : "=v"(r) : "v"(lo), "v"(hi));
  return r;
}

__device__ __forceinline__ void gload16(const void* g, void* l) {
  __builtin_amdgcn_global_load_lds(
      (const __attribute__((address_space(1))) unsigned int*)g,
      (__attribute__((address_space(3))) unsigned int*)l, 16, 0, 0);
}

// ---------------- fused prep: x->bf16 | weight transposes | mask scan+pad-zero ----------------
// blocks 0..4095: cvt x; 4096..8191: transpose Wq/Wkv/Wo; 8192..8193: mask scan for batch b.
__global__ __launch_bounds__(256) void prep(const float* __restrict__ x, short* __restrict__ xb,
                                            const float* __restrict__ Wq, const float* __restrict__ Wkv,
                                            const float* __restrict__ Wo, short* __restrict__ W1T,
                                            short* __restrict__ WoT, float qscale,
                                            const int* __restrict__ mask, int* __restrict__ pos,
                                            int* __restrict__ nvOut, short* __restrict__ QK,
                                            short* __restrict__ VT) {
  __shared__ float tbuf[32][33];
  __shared__ int part[256];
  __shared__ int nvLds;
  int bid = blockIdx.x;
  const int tid = threadIdx.x;

  if (bid < 4096) {                     // ---- x fp32 -> bf16 ----
    int i = bid * 256 + tid;
    float4 f = ((const float4*)x)[i];
    s16x4 o; o.x = f2bf(f.x); o.y = f2bf(f.y); o.z = f2bf(f.z); o.w = f2bf(f.w);
    ((s16x4*)xb)[i] = o;
    return;
  }
  bid -= 4096;
  if (bid < 4096) {                     // ---- weight transpose+convert(+scale) ----
    const float* in; short* out; int N; float scale;
    if (bid < 1024)      { in = Wq;  out = W1T;              N = 1024; scale = qscale; }
    else if (bid < 3072) { bid -= 1024; in = Wkv; out = W1T + 1024*1024; N = 2048; scale = 1.f; }
    else                 { bid -= 3072; in = Wo;  out = WoT;             N = 1024; scale = 1.f; }
    const int nb = N >> 5;
    const int nt = (bid % nb) * 32, kt = (bid / nb) * 32;
    const int tx = tid & 31, ty = tid >> 5;  // 32 x 8
    #pragma unroll
    for (int i = 0; i < 4; i++) tbuf[ty + 8*i][tx] = in[(size_t)(kt + ty + 8*i) * N + nt + tx];
    __syncthreads();
    #pragma unroll
    for (int i = 0; i < 4; i++)
      out[(size_t)(nt + ty + 8*i) * 1024 + kt + tx] = f2bf(tbuf[tx][ty + 8*i] * scale);
    return;
  }
  // ---- mask scan for batch b: pos[], nv, zero pad rows/cols ----
  const int b = bid - 4096;
  int loc[8], s = 0;
  #pragma unroll
  for (int j = 0; j < 8; j++) { loc[j] = mask[b*2048 + tid*8 + j] ? 1 : 0; s += loc[j]; }
  part[tid] = s;
  __syncthreads();
  if (tid == 0) {
    int run = 0;
    for (int i = 0; i < 256; i++) { int v = part[i]; part[i] = run; run += v; }
    nvOut[b] = run; nvLds = run;
  }
  __syncthreads();
  int run = part[tid];
  #pragma unroll
  for (int j = 0; j < 8; j++) { pos[b*2048 + tid*8 + j] = loc[j] ? run : -1; run += loc[j]; }
  const int nv = nvLds;
  const int padded = (nv + 63) & ~63;
  const int w = padded - nv;
  // zero K pad rows (QK cols 1024..2047), vectorized 8-short chunks
  s16x8 z8 = {0,0,0,0,0,0,0,0};
  for (int idx = tid; idx < w * 128; idx += 256) {
    int rr = idx >> 7, cc = idx & 127;
    *(s16x8*)&QK[((size_t)(b*2048 + nv + rr)) * 2048 + 1024 + cc*8] = z8;
  }
  // zero VT pad cols
  for (int idx = tid; idx < 1024 * w; idx += 256) {
    int dr = idx / w, col = nv + idx % w;
    VT[((size_t)(b*1024 + dr)) * 2048 + col] = 0;
  }
}

// ---------------- QKV GEMM (double-buffered): Q/K -> QK[4096][2048] (K rows compacted),
// V -> VT[(b*16+h)*64+d][n] scattered to compacted columns ----------------
__global__ __launch_bounds__(256) void gemm_qkv(const short* __restrict__ A,
                                                const short* __restrict__ Bt,
                                                short* __restrict__ QK,
                                                short* __restrict__ VT,
                                                const int* __restrict__ pos) {
  const int K = 1024;
  __shared__ short As[2][128][32];
  __shared__ short Bs[2][128][32];
  const int tid = threadIdx.x;
  const int wave = tid >> 6, lane = tid & 63;
  const int l15 = lane & 15, l4 = lane >> 4;
  const int bm = blockIdx.y * 128, bn = blockIdx.x * 128;
  const int wr = (wave >> 1) * 64, wc = (wave & 1) * 64;
  const int r = tid >> 2, c8 = (tid & 3) * 8;
  const short* aS0 = &A [(size_t)(bm + r)      * K + c8];
  const short* aS1 = &A [(size_t)(bm + 64 + r) * K + c8];
  const short* bS0 = &Bt[(size_t)(bn + r)      * K + c8];
  const short* bS1 = &Bt[(size_t)(bn + 64 + r) * K + c8];
  f32x4 acc[4][4] = {};
  gload16(aS0, (char*)As + tid*16);
  gload16(aS1, (char*)As + 4096 + tid*16);
  gload16(bS0, (char*)Bs + tid*16);
  gload16(bS1, (char*)Bs + 4096 + tid*16);
  __syncthreads();
  #pragma unroll 2
  for (int kk = 0; kk < 32; kk++) {
    const int cur = kk & 1;
    if (kk + 1 < 32) {
      const int k1 = (kk + 1) * 32;
      gload16(aS0 + k1, (char*)As + (cur^1)*8192 + tid*16);
      gload16(aS1 + k1, (char*)As + (cur^1)*8192 + 4096 + tid*16);
      gload16(bS0 + k1, (char*)Bs + (cur^1)*8192 + tid*16);
      gload16(bS1 + k1, (char*)Bs + (cur^1)*8192 + 4096 + tid*16);
    }
    s16x8 af[4], bf[4];
    #pragma unroll
    for (int m = 0; m < 4; m++) af[m] = *(const s16x8*)&As[cur][wr + m*16 + l15][l4*8];
    #pragma unroll
    for (int n = 0; n < 4; n++) bf[n] = *(const s16x8*)&Bs[cur][wc + n*16 + l15][l4*8];
    #pragma unroll
    for (int m = 0; m < 4; m++)
      #pragma unroll
      for (int n = 0; n < 4; n++)
        acc[m][n] = __builtin_amdgcn_mfma_f32_16x16x32_bf16(af[m], bf[n], acc[m][n], 0, 0, 0);
    __syncthreads();
  }
  #pragma unroll
  for (int m = 0; m < 4; m++) {
    const int row0 = bm + wr + m*16 + l4*4;
    const int b2 = row0 >> 11;          // batch
    int4 p4 = *(const int4*)&pos[row0]; // compacted positions for rows row0..row0+3
    const int pj[4] = {p4.x, p4.y, p4.z, p4.w};
    #pragma unroll
    for (int n = 0; n < 4; n++) {
      const int col = bn + wc + n*16 + l15;
      if (col < 1024) {                 // Q: direct
        #pragma unroll
        for (int j = 0; j < 4; j++)
          QK[(size_t)(row0 + j) * 2048 + col] = f2bf(acc[m][n][j]);
      } else if (col < 2048) {          // K: scatter rows to compacted positions
        #pragma unroll
        for (int j = 0; j < 4; j++)
          if (pj[j] >= 0)
            QK[((size_t)(b2*2048 + pj[j])) * 2048 + col] = f2bf(acc[m][n][j]);
      } else {                          // V: scatter columns of VT
        const int c2 = col - 2048;
        const size_t base = ((size_t)(b2*1024 + c2)) * 2048;
        #pragma unroll
        for (int j = 0; j < 4; j++)
          if (pj[j] >= 0) VT[base + pj[j]] = f2bf(acc[m][n][j]);
      }
    }
  }
}

// ---------------- out-proj GEMM (double-buffered): out f32 = O * WoT^T ----------------
__global__ __launch_bounds__(256) void gemm_out(const short* __restrict__ A,
                                                const short* __restrict__ Bt,
                                                float* __restrict__ C) {
  const int N = 1024, K = 1024;
  __shared__ short As[2][64][32];
  __shared__ short Bs[2][128][32];
  const int tid = threadIdx.x;
  const int wave = tid >> 6, lane = tid & 63;
  const int l15 = lane & 15, l4 = lane >> 4;
  const int bm = blockIdx.y * 64, bn = blockIdx.x * 128;
  const int wr = (wave >> 1) * 32, wc = (wave & 1) * 64;
  const int r = tid >> 2, c8 = (tid & 3) * 8;
  const short* aS0 = &A [(size_t)(bm + r)      * K + c8];
  const short* bS0 = &Bt[(size_t)(bn + r)      * K + c8];
  const short* bS1 = &Bt[(size_t)(bn + 64 + r) * K + c8];
  f32x4 acc[2][4] = {};
  if (r < 64) gload16(aS0, (char*)As + tid*16);
  gload16(bS0, (char*)Bs + tid*16);
  gload16(bS1, (char*)Bs + 4096 + tid*16);
  __syncthreads();
  #pragma unroll 2
  for (int kk = 0; kk < 32; kk++) {
    const int cur = kk & 1;
    if (kk + 1 < 32) {
      const int k1 = (kk + 1) * 32;
      gload16(aS0 + k1, (char*)As + (cur^1)*4096 + tid*16);
      gload16(bS0 + k1, (char*)Bs + (cur^1)*8192 + tid*16);
      gload16(bS1 + k1, (char*)Bs + (cur^1)*8192 + 4096 + tid*16);
    }
    s16x8 af[2], bf[4];
    #pragma unroll
    for (int m = 0; m < 2; m++) af[m] = *(const s16x8*)&As[cur][wr + m*16 + l15][l4*8];
    #pragma unroll
    for (int n = 0; n < 4; n++) bf[n] = *(const s16x8*)&Bs[cur][wc + n*16 + l15][l4*8];
    #pragma unroll
    for (int m = 0; m < 2; m++)
      #pragma unroll
      for (int n = 0; n < 4; n++)
        acc[m][n] = __builtin_amdgcn_mfma_f32_16x16x32_bf16(af[m], bf[n], acc[m][n], 0, 0, 0);
    __syncthreads();
  }
  #pragma unroll
  for (int m = 0; m < 2; m++)
    #pragma unroll
    for (int n = 0; n < 4; n++)
      #pragma unroll
      for (int j = 0; j < 4; j++) {
        int row = bm + wr + m*16 + l4*4 + j;
        int col = bn + wc + n*16 + l15;
        C[(size_t)row * N + col] = acc[m][n][j];
      }
}

// ---------------- fused flash attention over COMPACTED keys ----------------
// QBLK=128 (4 waves x 32 q-rows), KVBLK=64, K/V double-buffered LDS (XOR-swizzled),
// one __syncthreads per tile. Trip count nt = ceil(nv[b]/64); tail bias from nv.
__global__ __launch_bounds__(256) void attn_kernel(const short* __restrict__ QK,
                                                   const short* __restrict__ VT,
                                                   const int* __restrict__ nv,
                                                   short* __restrict__ O) {
  __shared__ short Ks[2][64*64];    // swizzled [key][d]
  __shared__ short Vs[2][64*64];    // swizzled [d][key]
  __shared__ short Pl[4][32*64];    // per-wave swizzled [q][key]

  // XCD swizzle: 512 blocks, 8 XCDs, 64 contiguous wgs each -> 4 heads/XCD
  const int orig = blockIdx.y * 16 + blockIdx.x;
  const int wg = (orig & 7) * 64 + (orig >> 3);
  const int qt = wg & 15;      // q tile of 128 rows
  const int bh = wg >> 4;      // 0..31
  const int b = bh >> 4, h = bh & 15;
  const int tid = threadIdx.x;
  const int wave = tid >> 6, lane = tid & 63;
  const int l15 = lane & 15, l4 = lane >> 4;

  const int nvb = nv[b];
  const int nt = (nvb + 63) >> 6;

  const int q0 = qt * 128 + wave * 32;
  s16x8 qb[2][2];
  #pragma unroll
  for (int qg = 0; qg < 2; qg++)
    #pragma unroll
    for (int s = 0; s < 2; s++)
      qb[qg][s] = *(const s16x8*)&QK[(size_t)(b*2048 + q0 + qg*16 + l15) * 2048 + h*64 + s*32 + l4*8];

  const int r0 = tid >> 3, c0 = tid & 7;
  const int cs = (c0 ^ (r0 & 7)) * 8;   // pre-swizzled source (shorts)
  const short* Kg = QK + (size_t)(b*2048)*2048 + 1024 + h*64;
  const short* Vg = VT + (size_t)(bh*64)*2048;
  const short* kS0 = Kg + (size_t)r0*2048 + cs;
  const short* kS1 = Kg + (size_t)(r0+32)*2048 + cs;
  const short* vS0 = Vg + (size_t)r0*2048 + cs;
  const short* vS1 = Vg + (size_t)(r0+32)*2048 + cs;

  gload16(kS0, (char*)Ks[0] + tid*16);
  gload16(kS1, (char*)Ks[0] + 4096 + tid*16);
  gload16(vS0, (char*)Vs[0] + tid*16);
  gload16(vS1, (char*)Vs[0] + 4096 + tid*16);
  __syncthreads();   // tile 0 ready

  f32x4 oacc[2][4] = {};
  float mrun[2] = {12.0f, 12.0f}, lsum[2] = {0.0f, 0.0f};
  const f32x4 zf = {0.f, 0.f, 0.f, 0.f};
  const int swz = (l15 & 7) << 4;
  char* PlB = (char*)&Pl[wave][0];

  #pragma unroll 2
  for (int kt = 0; kt < nt; kt++) {
    const int cur = kt & 1;
    if (kt + 1 < nt) {
      gload16(kS0 + (size_t)(kt+1)*131072, (char*)Ks[cur^1] + tid*16);
      gload16(kS1 + (size_t)(kt+1)*131072, (char*)Ks[cur^1] + 4096 + tid*16);
      gload16(vS0 + (kt+1)*64,             (char*)Vs[cur^1] + tid*16);
      gload16(vS1 + (kt+1)*64,             (char*)Vs[cur^1] + 4096 + tid*16);
    }
    const char* KsB = (const char*)Ks[cur];
    const char* VsB = (const char*)Vs[cur];
    const bool last = (kt == nt - 1);

    // ---- QK^T for both q-groups, K fragments loaded once ----
    s16x8 ka[4][2];
    #pragma unroll
    for (int g = 0; g < 4; g++) {
      ka[g][0] = *(const s16x8*)(KsB + (g*16 + l15)*128 + ((l4*16) ^ swz));
      ka[g][1] = *(const s16x8*)(KsB + (g*16 + l15)*128 + ((64 + l4*16) ^ swz));
    }
    f32x4 sv[2][4];
    #pragma unroll
    for (int g = 0; g < 4; g++) {
      f32x4 cb = zf;
      if (last) {
        const int k0i = kt*64 + g*16 + l4*4;
        #pragma unroll
        for (int rr = 0; rr < 4; rr++) cb[rr] = (k0i + rr < nvb) ? 0.f : -1e38f;
      }
      #pragma unroll
      for (int qg = 0; qg < 2; qg++) {
        f32x4 s = __builtin_amdgcn_mfma_f32_16x16x32_bf16(ka[g][0], qb[qg][0], cb, 0, 0, 0);
        sv[qg][g] = __builtin_amdgcn_mfma_f32_16x16x32_bf16(ka[g][1], qb[qg][1], s, 0, 0, 0);
      }
    }

    // ---- per q-group: softmax (defer-max), P write, PV ----
    #pragma unroll
    for (int qg = 0; qg < 2; qg++) {
      const int rowB = (qg*16 + l15) * 128;
      float p[16], psum = 0.f;
      #pragma unroll
      for (int g = 0; g < 4; g++)
        #pragma unroll
        for (int rr = 0; rr < 4; rr++) {
          p[g*4+rr] = __builtin_amdgcn_exp2f(sv[qg][g][rr] - mrun[qg]);
          psum += p[g*4+rr];
        }
      psum += __shfl_xor(psum, 16);
      psum += __shfl_xor(psum, 32);
      if (!__all(psum <= 512.0f)) {   // rare rescale path (wave-uniform)
        float tm = sv[qg][0][0];
        #pragma unroll
        for (int g = 0; g < 4; g++)
          #pragma unroll
          for (int rr = 0; rr < 4; rr++) tm = fmaxf(tm, sv[qg][g][rr]);
        tm = fmaxf(tm, __shfl_xor(tm, 16));
        tm = fmaxf(tm, __shfl_xor(tm, 32));
        float mnew = fmaxf(mrun[qg], tm);
        float corr = __builtin_amdgcn_exp2f(mrun[qg] - mnew);
        psum = 0.f;
        #pragma unroll
        for (int g = 0; g < 4; g++)
          #pragma unroll
          for (int rr = 0; rr < 4; rr++) {
            p[g*4+rr] = __builtin_amdgcn_exp2f(sv[qg][g][rr] - mnew);
            psum += p[g*4+rr];
          }
        psum += __shfl_xor(psum, 16);
        psum += __shfl_xor(psum, 32);
        #pragma unroll
        for (int f = 0; f < 4; f++)
          #pragma unroll
          for (int j = 0; j < 4; j++) oacc[qg][f][j] *= corr;
        lsum[qg] *= corr;
        mrun[qg] = mnew;
      }
      lsum[qg] += psum;
      #pragma unroll
      for (int g = 0; g < 4; g++) {
        uint2 pk2;
        pk2.x = cvtpk(p[g*4+0], p[g*4+1]);
        pk2.y = cvtpk(p[g*4+2], p[g*4+3]);
        *(uint2*)(PlB + rowB + ((g*32 + l4*8) ^ swz)) = pk2;
      }
      #pragma unroll
      for (int kh = 0; kh < 2; kh++) {
        s16x8 pb = *(const s16x8*)(PlB + rowB + ((kh*64 + l4*16) ^ swz));
        #pragma unroll
        for (int f = 0; f < 4; f++) {
          s16x8 vf = *(const s16x8*)(VsB + (f*16 + l15)*128 + ((kh*64 + l4*16) ^ swz));
          oacc[qg][f] = __builtin_amdgcn_mfma_f32_16x16x32_bf16(vf, pb, oacc[qg][f], 0, 0, 0);
        }
      }
    }
    __syncthreads();  // all waves done with buf[cur]; prefetch drained
  }

  #pragma unroll
  for (int qg = 0; qg < 2; qg++) {
    float inv = 1.0f / lsum[qg];
    #pragma unroll
    for (int f = 0; f < 4; f++) {
      uint2 o;
      o.x = cvtpk(oacc[qg][f][0] * inv, oacc[qg][f][1] * inv);
      o.y = cvtpk(oacc[qg][f][2] * inv, oacc[qg][f][3] * inv);
      *(uint2*)&O[(size_t)(b*2048 + q0 + qg*16 + l15) * 1024 + h*64 + f*16 + l4*4] = o;
    }
  }
}

extern "C" void kernel_launch(void* const* d_in, const int* in_sizes, int n_in,
                              void* d_out, int out_size, void* d_ws, size_t ws_size,
                              hipStream_t stream) {
  const float* x    = (const float*)d_in[0];
  const int*   mask = (const int*)  d_in[1];
  const float* Wq   = (const float*)d_in[2];
  const float* Wkv  = (const float*)d_in[3];
  const float* Wo   = (const float*)d_in[4];
  float* out = (float*)d_out;

  char* ws = (char*)d_ws;
  short* xb  = (short*)(ws);                 //  8 MB  [4096][1024]
  short* W1T = (short*)(ws + 8388608);       //  6 MB  [3072][1024]
  short* WoT = (short*)(ws + 14680064);      //  2 MB  [1024][1024]
  short* QK  = (short*)(ws + 16777216);      // 16 MB  [4096][2048]  Q | compacted K
  short* VT  = (short*)(ws + 33554432);      //  8 MB  [2048][2048]  compacted V^T
  short* O   = (short*)(ws + 41943040);      //  8 MB  [4096][1024]
  int*   pos = (int*)  (ws + 50331648);      // 16 KB  [4096]
  int*   nvP = (int*)  (ws + 50348032);      //  8 B   [2]

  const float qscale = 0.18033688011112042f;  // dh^-0.5 * log2(e)

  prep<<<8194, 256, 0, stream>>>(x, xb, Wq, Wkv, Wo, W1T, WoT, qscale, mask, pos, nvP, QK, VT);
  gemm_qkv<<<dim3(24, 32), 256, 0, stream>>>(xb, W1T, QK, VT, pos);
  attn_kernel<<<dim3(16, 32), 256, 0, stream>>>(QK, VT, nvP, O);
  gemm_out<<<dim3(8, 64), 256, 0, stream>>>(O, WoT, out);
}

// Round 9
// 177.263 us; speedup vs baseline: 1.1820x; 1.1820x over previous
//
#include <hip/hip_runtime.h>
#include <stdint.h>

typedef __attribute__((ext_vector_type(4))) float f32x4;
typedef __attribute__((ext_vector_type(8))) short s16x8;
typedef __attribute__((ext_vector_type(4))) short s16x4;

// Problem constants: B=2, N=2048, DIM=1024, H=16, DH=64, DI=1024, M = B*N = 4096

__device__ __forceinline__ short f2bf(float f) {
  union { float f; unsigned u; } v; v.f = f;
  unsigned r = (v.u + 0x7fff + ((v.u >> 16) & 1)) >> 16;  // RNE
  return (short)r;
}

__device__ __forceinline__ unsigned cvtpk(float lo, float hi) {
  unsigned r;
  asm("v_cvt_pk_bf16_f32 %0, %1, %2" : "=v"(r) : "v"(lo), "v"(hi));
  return r;
}

__device__ __forceinline__ void gload16(const void* g, void* l) {
  __builtin_amdgcn_global_load_lds(
      (const __attribute__((address_space(1))) unsigned int*)g,
      (__attribute__((address_space(3))) unsigned int*)l, 16, 0, 0);
}

// ---------------- fused prep: x->bf16 | weight transposes | mask scan ----------------
// blocks 0..4095: cvt x; 4096..8191: transpose Wq/Wkv/Wo; 8192..8193: mask scan.
// NOTE: no pad zeroing — pad K rows / V cols stay 0xAA poison (finite bf16);
// attn's tail bias forces P=0 there, and 0 x finite = 0 in MFMA. Exact.
__global__ __launch_bounds__(256) void prep(const float* __restrict__ x, short* __restrict__ xb,
                                            const float* __restrict__ Wq, const float* __restrict__ Wkv,
                                            const float* __restrict__ Wo, short* __restrict__ W1T,
                                            short* __restrict__ WoT, float qscale,
                                            const int* __restrict__ mask, int* __restrict__ pos,
                                            int* __restrict__ nvOut) {
  __shared__ float tbuf[32][33];
  __shared__ int part[256];
  int bid = blockIdx.x;
  const int tid = threadIdx.x;

  if (bid < 4096) {                     // ---- x fp32 -> bf16 ----
    int i = bid * 256 + tid;
    float4 f = ((const float4*)x)[i];
    s16x4 o; o.x = f2bf(f.x); o.y = f2bf(f.y); o.z = f2bf(f.z); o.w = f2bf(f.w);
    ((s16x4*)xb)[i] = o;
    return;
  }
  bid -= 4096;
  if (bid < 4096) {                     // ---- weight transpose+convert(+scale) ----
    const float* in; short* out; int N; float scale;
    if (bid < 1024)      { in = Wq;  out = W1T;              N = 1024; scale = qscale; }
    else if (bid < 3072) { bid -= 1024; in = Wkv; out = W1T + 1024*1024; N = 2048; scale = 1.f; }
    else                 { bid -= 3072; in = Wo;  out = WoT;             N = 1024; scale = 1.f; }
    const int nb = N >> 5;
    const int nt = (bid % nb) * 32, kt = (bid / nb) * 32;
    const int tx = tid & 31, ty = tid >> 5;  // 32 x 8
    #pragma unroll
    for (int i = 0; i < 4; i++) tbuf[ty + 8*i][tx] = in[(size_t)(kt + ty + 8*i) * N + nt + tx];
    __syncthreads();
    #pragma unroll
    for (int i = 0; i < 4; i++)
      out[(size_t)(nt + ty + 8*i) * 1024 + kt + tx] = f2bf(tbuf[tx][ty + 8*i] * scale);
    return;
  }
  // ---- mask scan for batch b: pos[], nv ----
  const int b = bid - 4096;
  int loc[8], s = 0;
  #pragma unroll
  for (int j = 0; j < 8; j++) { loc[j] = mask[b*2048 + tid*8 + j] ? 1 : 0; s += loc[j]; }
  part[tid] = s;
  __syncthreads();
  if (tid == 0) {
    int run = 0;
    for (int i = 0; i < 256; i++) { int v = part[i]; part[i] = run; run += v; }
    nvOut[b] = run;
  }
  __syncthreads();
  int run = part[tid];
  #pragma unroll
  for (int j = 0; j < 8; j++) { pos[b*2048 + tid*8 + j] = loc[j] ? run : -1; run += loc[j]; }
}

// ---------------- QKV GEMM: depth-2 prefetch, counted vmcnt, 3 LDS buffers ----------------
// Q/K -> QK[4096][2048] (K rows compacted), V -> VT scattered to compacted cols.
__global__ __launch_bounds__(256) void gemm_qkv(const short* __restrict__ A,
                                                const short* __restrict__ Bt,
                                                short* __restrict__ QK,
                                                short* __restrict__ VT,
                                                const int* __restrict__ pos) {
  const int K = 1024;
  __shared__ short As[3][128][32];   // 3 x 8 KB
  __shared__ short Bs[3][128][32];   // 3 x 8 KB  (48 KB total -> 3 blocks/CU)
  const int tid = threadIdx.x;
  const int wave = tid >> 6, lane = tid & 63;
  const int l15 = lane & 15, l4 = lane >> 4;
  // bijective XCD swizzle: 768 blocks = 8 XCDs x 96; each XCD gets 4 full rows
  const int lin = blockIdx.y * 24 + blockIdx.x;
  const int wgs = (lin & 7) * 96 + (lin >> 3);
  const int bm = (wgs / 24) * 128, bn = (wgs % 24) * 128;
  const int wr = (wave >> 1) * 64, wc = (wave & 1) * 64;
  const int r = tid >> 2, c8 = (tid & 3) * 8;
  const short* aS0 = &A [(size_t)(bm + r)      * K + c8];
  const short* aS1 = &A [(size_t)(bm + 64 + r) * K + c8];
  const short* bS0 = &Bt[(size_t)(bn + r)      * K + c8];
  const short* bS1 = &Bt[(size_t)(bn + 64 + r) * K + c8];
  f32x4 acc[4][4] = {};

#define QKV_STAGE(s) { const int k1_ = (s) * 32; \
    char* aD_ = (char*)As + ((s) % 3) * 8192;    \
    char* bD_ = (char*)Bs + ((s) % 3) * 8192;    \
    gload16(aS0 + k1_, aD_ + tid*16);            \
    gload16(aS1 + k1_, aD_ + 4096 + tid*16);     \
    gload16(bS0 + k1_, bD_ + tid*16);            \
    gload16(bS1 + k1_, bD_ + 4096 + tid*16); }

  QKV_STAGE(0);
  QKV_STAGE(1);
  for (int kk = 0; kk < 32; kk++) {
    if (kk + 2 < 32) QKV_STAGE(kk + 2);
    // wait until stage(kk) complete; stages kk+1, kk+2 stay in flight
    if (kk < 30)       asm volatile("s_waitcnt vmcnt(8)" ::: "memory");
    else if (kk == 30) asm volatile("s_waitcnt vmcnt(4)" ::: "memory");
    else               asm volatile("s_waitcnt vmcnt(0)" ::: "memory");
    __builtin_amdgcn_sched_barrier(0);
    __builtin_amdgcn_s_barrier();
    __builtin_amdgcn_sched_barrier(0);
    const int cur = kk % 3;
    s16x8 af[4], bf[4];
    #pragma unroll
    for (int m = 0; m < 4; m++) af[m] = *(const s16x8*)&As[cur][wr + m*16 + l15][l4*8];
    #pragma unroll
    for (int n = 0; n < 4; n++) bf[n] = *(const s16x8*)&Bs[cur][wc + n*16 + l15][l4*8];
    #pragma unroll
    for (int m = 0; m < 4; m++)
      #pragma unroll
      for (int n = 0; n < 4; n++)
        acc[m][n] = __builtin_amdgcn_mfma_f32_16x16x32_bf16(af[m], bf[n], acc[m][n], 0, 0, 0);
    __builtin_amdgcn_sched_barrier(0);
    __builtin_amdgcn_s_barrier();   // readers done before buf[cur] is restaged
  }
#undef QKV_STAGE

  #pragma unroll
  for (int m = 0; m < 4; m++) {
    const int row0 = bm + wr + m*16 + l4*4;
    const int b2 = row0 >> 11;          // batch
    int4 p4 = *(const int4*)&pos[row0];
    const int pj[4] = {p4.x, p4.y, p4.z, p4.w};
    #pragma unroll
    for (int n = 0; n < 4; n++) {
      const int col = bn + wc + n*16 + l15;
      if (col < 1024) {                 // Q: direct
        #pragma unroll
        for (int j = 0; j < 4; j++)
          QK[(size_t)(row0 + j) * 2048 + col] = f2bf(acc[m][n][j]);
      } else if (col < 2048) {          // K: scatter rows to compacted positions
        #pragma unroll
        for (int j = 0; j < 4; j++)
          if (pj[j] >= 0)
            QK[((size_t)(b2*2048 + pj[j])) * 2048 + col] = f2bf(acc[m][n][j]);
      } else {                          // V: scatter columns of VT
        const int c2 = col - 2048;
        const size_t base = ((size_t)(b2*1024 + c2)) * 2048;
        #pragma unroll
        for (int j = 0; j < 4; j++)
          if (pj[j] >= 0) VT[base + pj[j]] = f2bf(acc[m][n][j]);
      }
    }
  }
}

// ---------------- out-proj GEMM: depth-2 prefetch, counted vmcnt ----------------
__global__ __launch_bounds__(256) void gemm_out(const short* __restrict__ A,
                                                const short* __restrict__ Bt,
                                                float* __restrict__ C) {
  const int N = 1024, K = 1024;
  __shared__ short As[3][64][32];    // 3 x 4 KB
  __shared__ short Bs[3][128][32];   // 3 x 8 KB
  const int tid = threadIdx.x;
  const int wave = tid >> 6, lane = tid & 63;
  const int l15 = lane & 15, l4 = lane >> 4;
  // bijective XCD swizzle: 512 blocks = 8 XCDs x 64
  const int lin = blockIdx.y * 8 + blockIdx.x;
  const int wgs = (lin & 7) * 64 + (lin >> 3);
  const int bm = (wgs >> 3) * 64, bn = (wgs & 7) * 128;
  const int wr = (wave >> 1) * 32, wc = (wave & 1) * 64;
  const int r = tid >> 2, c8 = (tid & 3) * 8;
  const short* aS0 = &A [(size_t)(bm + r)      * K + c8];
  const short* bS0 = &Bt[(size_t)(bn + r)      * K + c8];
  const short* bS1 = &Bt[(size_t)(bn + 64 + r) * K + c8];
  f32x4 acc[2][4] = {};

#define OUT_STAGE(s) { const int k1_ = (s) * 32; \
    char* aD_ = (char*)As + ((s) % 3) * 4096;    \
    char* bD_ = (char*)Bs + ((s) % 3) * 8192;    \
    gload16(aS0 + k1_, aD_ + tid*16);            \
    gload16(bS0 + k1_, bD_ + tid*16);            \
    gload16(bS1 + k1_, bD_ + 4096 + tid*16); }

  OUT_STAGE(0);
  OUT_STAGE(1);
  for (int kk = 0; kk < 32; kk++) {
    if (kk + 2 < 32) OUT_STAGE(kk + 2);
    if (kk < 30)       asm volatile("s_waitcnt vmcnt(6)" ::: "memory");
    else if (kk == 30) asm volatile("s_waitcnt vmcnt(3)" ::: "memory");
    else               asm volatile("s_waitcnt vmcnt(0)" ::: "memory");
    __builtin_amdgcn_sched_barrier(0);
    __builtin_amdgcn_s_barrier();
    __builtin_amdgcn_sched_barrier(0);
    const int cur = kk % 3;
    s16x8 af[2], bf[4];
    #pragma unroll
    for (int m = 0; m < 2; m++) af[m] = *(const s16x8*)&As[cur][wr + m*16 + l15][l4*8];
    #pragma unroll
    for (int n = 0; n < 4; n++) bf[n] = *(const s16x8*)&Bs[cur][wc + n*16 + l15][l4*8];
    #pragma unroll
    for (int m = 0; m < 2; m++)
      #pragma unroll
      for (int n = 0; n < 4; n++)
        acc[m][n] = __builtin_amdgcn_mfma_f32_16x16x32_bf16(af[m], bf[n], acc[m][n], 0, 0, 0);
    __builtin_amdgcn_sched_barrier(0);
    __builtin_amdgcn_s_barrier();
  }
#undef OUT_STAGE

  #pragma unroll
  for (int m = 0; m < 2; m++)
    #pragma unroll
    for (int n = 0; n < 4; n++)
      #pragma unroll
      for (int j = 0; j < 4; j++) {
        int row = bm + wr + m*16 + l4*4 + j;
        int col = bn + wc + n*16 + l15;
        C[(size_t)row * N + col] = acc[m][n][j];
      }
}

// ---------------- fused flash attention over COMPACTED keys (unchanged from R8) ----------------
__global__ __launch_bounds__(256) void attn_kernel(const short* __restrict__ QK,
                                                   const short* __restrict__ VT,
                                                   const int* __restrict__ nv,
                                                   short* __restrict__ O) {
  __shared__ short Ks[2][64*64];    // swizzled [key][d]
  __shared__ short Vs[2][64*64];    // swizzled [d][key]
  __shared__ short Pl[4][32*64];    // per-wave swizzled [q][key]

  const int orig = blockIdx.y * 16 + blockIdx.x;
  const int wg = (orig & 7) * 64 + (orig >> 3);
  const int qt = wg & 15;
  const int bh = wg >> 4;
  const int b = bh >> 4, h = bh & 15;
  const int tid = threadIdx.x;
  const int wave = tid >> 6, lane = tid & 63;
  const int l15 = lane & 15, l4 = lane >> 4;

  const int nvb = nv[b];
  const int nt = (nvb + 63) >> 6;

  const int q0 = qt * 128 + wave * 32;
  s16x8 qb[2][2];
  #pragma unroll
  for (int qg = 0; qg < 2; qg++)
    #pragma unroll
    for (int s = 0; s < 2; s++)
      qb[qg][s] = *(const s16x8*)&QK[(size_t)(b*2048 + q0 + qg*16 + l15) * 2048 + h*64 + s*32 + l4*8];

  const int r0 = tid >> 3, c0 = tid & 7;
  const int cs = (c0 ^ (r0 & 7)) * 8;
  const short* Kg = QK + (size_t)(b*2048)*2048 + 1024 + h*64;
  const short* Vg = VT + (size_t)(bh*64)*2048;
  const short* kS0 = Kg + (size_t)r0*2048 + cs;
  const short* kS1 = Kg + (size_t)(r0+32)*2048 + cs;
  const short* vS0 = Vg + (size_t)r0*2048 + cs;
  const short* vS1 = Vg + (size_t)(r0+32)*2048 + cs;

  gload16(kS0, (char*)Ks[0] + tid*16);
  gload16(kS1, (char*)Ks[0] + 4096 + tid*16);
  gload16(vS0, (char*)Vs[0] + tid*16);
  gload16(vS1, (char*)Vs[0] + 4096 + tid*16);
  __syncthreads();

  f32x4 oacc[2][4] = {};
  float mrun[2] = {12.0f, 12.0f}, lsum[2] = {0.0f, 0.0f};
  const f32x4 zf = {0.f, 0.f, 0.f, 0.f};
  const int swz = (l15 & 7) << 4;
  char* PlB = (char*)&Pl[wave][0];

  #pragma unroll 2
  for (int kt = 0; kt < nt; kt++) {
    const int cur = kt & 1;
    if (kt + 1 < nt) {
      gload16(kS0 + (size_t)(kt+1)*131072, (char*)Ks[cur^1] + tid*16);
      gload16(kS1 + (size_t)(kt+1)*131072, (char*)Ks[cur^1] + 4096 + tid*16);
      gload16(vS0 + (kt+1)*64,             (char*)Vs[cur^1] + tid*16);
      gload16(vS1 + (kt+1)*64,             (char*)Vs[cur^1] + 4096 + tid*16);
    }
    const char* KsB = (const char*)Ks[cur];
    const char* VsB = (const char*)Vs[cur];
    const bool last = (kt == nt - 1);

    s16x8 ka[4][2];
    #pragma unroll
    for (int g = 0; g < 4; g++) {
      ka[g][0] = *(const s16x8*)(KsB + (g*16 + l15)*128 + ((l4*16) ^ swz));
      ka[g][1] = *(const s16x8*)(KsB + (g*16 + l15)*128 + ((64 + l4*16) ^ swz));
    }
    f32x4 sv[2][4];
    #pragma unroll
    for (int g = 0; g < 4; g++) {
      f32x4 cb = zf;
      if (last) {
        const int k0i = kt*64 + g*16 + l4*4;
        #pragma unroll
        for (int rr = 0; rr < 4; rr++) cb[rr] = (k0i + rr < nvb) ? 0.f : -1e38f;
      }
      #pragma unroll
      for (int qg = 0; qg < 2; qg++) {
        f32x4 s = __builtin_amdgcn_mfma_f32_16x16x32_bf16(ka[g][0], qb[qg][0], cb, 0, 0, 0);
        sv[qg][g] = __builtin_amdgcn_mfma_f32_16x16x32_bf16(ka[g][1], qb[qg][1], s, 0, 0, 0);
      }
    }

    #pragma unroll
    for (int qg = 0; qg < 2; qg++) {
      const int rowB = (qg*16 + l15) * 128;
      float p[16], psum = 0.f;
      #pragma unroll
      for (int g = 0; g < 4; g++)
        #pragma unroll
        for (int rr = 0; rr < 4; rr++) {
          p[g*4+rr] = __builtin_amdgcn_exp2f(sv[qg][g][rr] - mrun[qg]);
          psum += p[g*4+rr];
        }
      psum += __shfl_xor(psum, 16);
      psum += __shfl_xor(psum, 32);
      if (!__all(psum <= 512.0f)) {
        float tm = sv[qg][0][0];
        #pragma unroll
        for (int g = 0; g < 4; g++)
          #pragma unroll
          for (int rr = 0; rr < 4; rr++) tm = fmaxf(tm, sv[qg][g][rr]);
        tm = fmaxf(tm, __shfl_xor(tm, 16));
        tm = fmaxf(tm, __shfl_xor(tm, 32));
        float mnew = fmaxf(mrun[qg], tm);
        float corr = __builtin_amdgcn_exp2f(mrun[qg] - mnew);
        psum = 0.f;
        #pragma unroll
        for (int g = 0; g < 4; g++)
          #pragma unroll
          for (int rr = 0; rr < 4; rr++) {
            p[g*4+rr] = __builtin_amdgcn_exp2f(sv[qg][g][rr] - mnew);
            psum += p[g*4+rr];
          }
        psum += __shfl_xor(psum, 16);
        psum += __shfl_xor(psum, 32);
        #pragma unroll
        for (int f = 0; f < 4; f++)
          #pragma unroll
          for (int j = 0; j < 4; j++) oacc[qg][f][j] *= corr;
        lsum[qg] *= corr;
        mrun[qg] = mnew;
      }
      lsum[qg] += psum;
      #pragma unroll
      for (int g = 0; g < 4; g++) {
        uint2 pk2;
        pk2.x = cvtpk(p[g*4+0], p[g*4+1]);
        pk2.y = cvtpk(p[g*4+2], p[g*4+3]);
        *(uint2*)(PlB + rowB + ((g*32 + l4*8) ^ swz)) = pk2;
      }
      #pragma unroll
      for (int kh = 0; kh < 2; kh++) {
        s16x8 pb = *(const s16x8*)(PlB + rowB + ((kh*64 + l4*16) ^ swz));
        #pragma unroll
        for (int f = 0; f < 4; f++) {
          s16x8 vf = *(const s16x8*)(VsB + (f*16 + l15)*128 + ((kh*64 + l4*16) ^ swz));
          oacc[qg][f] = __builtin_amdgcn_mfma_f32_16x16x32_bf16(vf, pb, oacc[qg][f], 0, 0, 0);
        }
      }
    }
    __syncthreads();
  }

  #pragma unroll
  for (int qg = 0; qg < 2; qg++) {
    float inv = 1.0f / lsum[qg];
    #pragma unroll
    for (int f = 0; f < 4; f++) {
      uint2 o;
      o.x = cvtpk(oacc[qg][f][0] * inv, oacc[qg][f][1] * inv);
      o.y = cvtpk(oacc[qg][f][2] * inv, oacc[qg][f][3] * inv);
      *(uint2*)&O[(size_t)(b*2048 + q0 + qg*16 + l15) * 1024 + h*64 + f*16 + l4*4] = o;
    }
  }
}

extern "C" void kernel_launch(void* const* d_in, const int* in_sizes, int n_in,
                              void* d_out, int out_size, void* d_ws, size_t ws_size,
                              hipStream_t stream) {
  const float* x    = (const float*)d_in[0];
  const int*   mask = (const int*)  d_in[1];
  const float* Wq   = (const float*)d_in[2];
  const float* Wkv  = (const float*)d_in[3];
  const float* Wo   = (const float*)d_in[4];
  float* out = (float*)d_out;

  char* ws = (char*)d_ws;
  short* xb  = (short*)(ws);                 //  8 MB  [4096][1024]
  short* W1T = (short*)(ws + 8388608);       //  6 MB  [3072][1024]
  short* WoT = (short*)(ws + 14680064);      //  2 MB  [1024][1024]
  short* QK  = (short*)(ws + 16777216);      // 16 MB  [4096][2048]  Q | compacted K
  short* VT  = (short*)(ws + 33554432);      //  8 MB  [2048][2048]  compacted V^T
  short* O   = (short*)(ws + 41943040);      //  8 MB  [4096][1024]
  int*   pos = (int*)  (ws + 50331648);      // 16 KB  [4096]
  int*   nvP = (int*)  (ws + 50348032);      //  8 B   [2]

  const float qscale = 0.18033688011112042f;  // dh^-0.5 * log2(e)

  prep<<<8194, 256, 0, stream>>>(x, xb, Wq, Wkv, Wo, W1T, WoT, qscale, mask, pos, nvP);
  gemm_qkv<<<dim3(24, 32), 256, 0, stream>>>(xb, W1T, QK, VT, pos);
  attn_kernel<<<dim3(16, 32), 256, 0, stream>>>(QK, VT, nvP, O);
  gemm_out<<<dim3(8, 64), 256, 0, stream>>>(O, WoT, out);
}